// Round 6
// baseline (352.791 us; speedup 1.0000x reference)
//
#include <hip/hip_runtime.h>
#include <hip/hip_bf16.h>
#include <hip/hip_cooperative_groups.h>

namespace cg = cooperative_groups;

#define NB    2
#define NK    2048
#define NPTS  16384
#define NBK   4096            // NB*NK
#define MSAMP 65536.0f        // NBK*16 samples per scale for BN0/BN1
#define MROW  4096.0f         // rows for final BN

#define NXB   88              // x bins (140 / 1.6)
#define NYB   50              // y bins (80 / 1.6)
#define NBIN  4400            // NXB*NYB
#define BSTRIDE 4416          // padded per-batch bin stride (incl. sentinel)
#define QBLOCKS 64            // query grid

__device__ __forceinline__ void binof(float x, float y, int& bx, int& by) {
  bx = min(NXB - 1, max(0, (int)floorf((x + 70.f) * 0.625f)));
  by = min(NYB - 1, max(0, (int)floorf((y + 40.f) * 0.625f)));
}

// insert (v=orig idx, p=payload) into ascending-by-idx 16-slot list
__device__ __forceinline__ void insert16(int v, int p, int* li, int* lp) {
#pragma unroll
  for (int k = 0; k < 16; k++) {
    const bool ins = v < li[k];
    const int tv = li[k], tp = lp[k];
    li[k] = ins ? v : tv;
    lp[k] = ins ? p : tp;
    v = ins ? tv : v;
    p = ins ? tp : p;
  }
}

// ---------------------------------------------------------------------------
// K1: BEV bilinear interpolation -> feats[:, 0:256]
// ---------------------------------------------------------------------------
__global__ __launch_bounds__(256) void bev_kernel(
    const float* __restrict__ kp, const float* __restrict__ bev,
    const int* __restrict__ stridep, float* __restrict__ feats)
{
  const int bk = blockIdx.x;           // 0..4095
  const int c  = threadIdx.x;          // channel 0..255
  const int b  = bk >> 11;
  const float st = (float)(*stridep);
  const float x = (kp[bk*3+0] - (-70.4f)) / 0.1f / st;
  const float y = (kp[bk*3+1] - (-40.0f)) / 0.1f / st;
  const int xf = (int)floorf(x), yf = (int)floorf(y);
  const int x0 = min(max(xf, 0), 175), x1 = min(max(xf + 1, 0), 175);
  const int y0 = min(max(yf, 0), 99),  y1 = min(max(yf + 1, 0), 99);
  const float x0f = (float)x0, x1f = (float)x1, y0f = (float)y0, y1f = (float)y1;
  const float wa = (x1f - x) * (y1f - y);
  const float wb = (x1f - x) * (y - y0f);
  const float wc = (x - x0f) * (y1f - y);
  const float wd = (x - x0f) * (y - y0f);
  const size_t base = ((size_t)b * 256 + c) * 17600;  // 100*176
  const float Ia = bev[base + y0 * 176 + x0];
  const float Ib = bev[base + y1 * 176 + x0];
  const float Ic = bev[base + y0 * 176 + x1];
  const float Id = bev[base + y1 * 176 + x1];
  feats[(size_t)bk * 304 + c] = Ia * wa + Ib * wb + Ic * wc + Id * wd;
}

// ---------------------------------------------------------------------------
// K2a: per-batch bin histogram + exclusive scan. 2 blocks (1/batch).
// ---------------------------------------------------------------------------
__global__ __launch_bounds__(256) void build_kernel(
    const float* __restrict__ pts, int* __restrict__ bin_start,
    int* __restrict__ bin_fill)
{
  __shared__ int hist[NBIN];
  __shared__ int wpart[4];
  const int b = blockIdx.x;
  const int t = threadIdx.x;
  for (int i = t; i < NBIN; i += 256) hist[i] = 0;
  __syncthreads();
  const float* px = pts + (size_t)b * NPTS * 3;
  for (int i = t; i < NPTS; i += 256) {
    const float x = px[i*3+0], y = px[i*3+1];
    int bx, by; binof(x, y, bx, by);
    atomicAdd(&hist[by * NXB + bx], 1);
  }
  __syncthreads();
  // chunked exclusive scan: 256 threads x 18 bins
  const int lo = t * 18, hi = min(NBIN, lo + 18);
  int s = 0;
  for (int i = lo; i < hi; i++) s += hist[i];
  const int lane = t & 63, wave = t >> 6;
  int x = s;
  #pragma unroll
  for (int d = 1; d < 64; d <<= 1) {
    const int y = __shfl_up(x, d);
    if (lane >= d) x += y;
  }
  if (lane == 63) wpart[wave] = x;
  __syncthreads();
  int base = 0;
  for (int wv = 0; wv < wave; wv++) base += wpart[wv];
  int run = base + x - s;                 // exclusive prefix of this chunk
  const int bb = b * BSTRIDE;
  for (int i = lo; i < hi; i++) {
    bin_start[bb + i] = run;
    bin_fill[bb + i]  = run;
    run += hist[i];
  }
  if (t == 0) bin_start[bb + NBIN] = NPTS;   // sentinel
}

// ---------------------------------------------------------------------------
// K2b: counting-sort scatter. 128 blocks x 256.
// ---------------------------------------------------------------------------
__global__ __launch_bounds__(256) void scatter_kernel(
    const float* __restrict__ pts, const float* __restrict__ pfeat,
    int* __restrict__ bin_fill, float4* __restrict__ sorted,
    int* __restrict__ sidx)
{
  const int gid = blockIdx.x * 256 + threadIdx.x;   // 0..32767
  const int b = gid >> 14;
  const int i = gid & (NPTS - 1);
  const float* px = pts + (size_t)b * NPTS * 3;
  const float x = px[i*3+0], y = px[i*3+1], z = px[i*3+2];
  const float f = pfeat[(size_t)b * NPTS + i];
  int bx, by; binof(x, y, bx, by);
  const int pos = atomicAdd(&bin_fill[b * BSTRIDE + by * NXB + bx], 1);
  sorted[(size_t)b * NPTS + pos] = make_float4(x, y, z, f);
  sidx[(size_t)b * NPTS + pos] = i;
}

// ---------------------------------------------------------------------------
// K2c: binned ball query. 1 thread per keypoint (64 blocks x 64).
// Exact first-16-by-original-index semantics via sorted insertion.
// ---------------------------------------------------------------------------
__global__ __launch_bounds__(64) void query_kernel(
    const float* __restrict__ kp, const int* __restrict__ bin_start,
    const float4* __restrict__ sorted, const int* __restrict__ sidx,
    float* __restrict__ g0buf, float* __restrict__ g1buf,
    int* __restrict__ cnt, float* __restrict__ part0)
{
  const int t = threadIdx.x;
  const int bk = blockIdx.x * 64 + t;      // 0..4095
  const int b = bk >> 11;
  const float kx = kp[bk*3+0], ky = kp[bk*3+1], kz = kp[bk*3+2];
  const int bb = b * BSTRIDE;
  const int b2 = b * NPTS;

  int li0[16], lp0[16], li1[16], lp1[16];
  #pragma unroll
  for (int k = 0; k < 16; k++) { li0[k] = 0x7fffffff; li1[k] = 0x7fffffff; lp0[k] = 0; lp1[k] = 0; }
  int c0 = 0, c1 = 0;

  const int bx0 = max(0,       (int)floorf((kx - 0.801f + 70.f) * 0.625f));
  const int bx1 = min(NXB - 1, (int)floorf((kx + 0.801f + 70.f) * 0.625f));
  const int by0 = max(0,       (int)floorf((ky - 0.801f + 40.f) * 0.625f));
  const int by1 = min(NYB - 1, (int)floorf((ky + 0.801f + 40.f) * 0.625f));

  for (int by = by0; by <= by1; by++) {
    for (int bx = bx0; bx <= bx1; bx++) {
      const int bin = by * NXB + bx;
      const int s = bin_start[bb + bin];
      const int e = bin_start[bb + bin + 1];
      for (int p = s; p < e; p++) {
        const float4 P = sorted[b2 + p];
        const float dx = P.x - kx, dy = P.y - ky, dz = P.z - kz;
        const float d2 = dx*dx + dy*dy + dz*dz;
        if (d2 < 0.64f) {
          const int oi = sidx[b2 + p];
          insert16(oi, p, li1, lp1); c1++;
          if (d2 < 0.16f) { insert16(oi, p, li0, lp0); c0++; }
        }
      }
    }
  }

  float m0[14], m1[14];
  #pragma unroll
  for (int i = 0; i < 14; i++) { m0[i] = 0.f; m1[i] = 0.f; }

  {
    const int n0 = min(c0, 16);
    float s0x = 0.f, s0y = 0.f, s0z = 0.f, s0f = 0.f;
    float4* gout = (float4*)(g0buf + (size_t)bk * 64);
    #pragma unroll
    for (int k = 0; k < 16; k++) {
      float dx, dy, dz, ff;
      if (k < n0) {
        const float4 P = sorted[b2 + lp0[k]];
        dx = P.x - kx; dy = P.y - ky; dz = P.z - kz; ff = P.w;
      } else {
        dx = s0x; dy = s0y; dz = s0z; ff = s0f;
      }
      if (k == 0 && n0 > 0) { s0x = dx; s0y = dy; s0z = dz; s0f = ff; }
      gout[k] = make_float4(dx, dy, dz, ff);
      m0[0] += dx; m0[1] += dy; m0[2] += dz; m0[3] += ff;
      m0[4] += dx*dx; m0[5] += dx*dy; m0[6] += dx*dz; m0[7] += dx*ff;
      m0[8] += dy*dy; m0[9] += dy*dz; m0[10] += dy*ff;
      m0[11] += dz*dz; m0[12] += dz*ff; m0[13] += ff*ff;
    }
  }
  {
    const int n1 = min(c1, 16);
    float s0x = 0.f, s0y = 0.f, s0z = 0.f, s0f = 0.f;
    float4* gout = (float4*)(g1buf + (size_t)bk * 64);
    #pragma unroll
    for (int k = 0; k < 16; k++) {
      float dx, dy, dz, ff;
      if (k < n1) {
        const float4 P = sorted[b2 + lp1[k]];
        dx = P.x - kx; dy = P.y - ky; dz = P.z - kz; ff = P.w;
      } else {
        dx = s0x; dy = s0y; dz = s0z; ff = s0f;
      }
      if (k == 0 && n1 > 0) { s0x = dx; s0y = dy; s0z = dz; s0f = ff; }
      gout[k] = make_float4(dx, dy, dz, ff);
      m1[0] += dx; m1[1] += dy; m1[2] += dz; m1[3] += ff;
      m1[4] += dx*dx; m1[5] += dx*dy; m1[6] += dx*dz; m1[7] += dx*ff;
      m1[8] += dy*dy; m1[9] += dy*dz; m1[10] += dy*ff;
      m1[11] += dz*dz; m1[12] += dz*ff; m1[13] += ff*ff;
    }
  }
  cnt[bk] = c0;
  cnt[NBK + bk] = c1;

  // wave reduction of 28 moment values -> part0[block][28]
  float mm[28];
  #pragma unroll
  for (int i = 0; i < 14; i++) { mm[i] = m0[i]; mm[14 + i] = m1[i]; }
  #pragma unroll
  for (int d = 1; d < 64; d <<= 1) {
    #pragma unroll
    for (int i = 0; i < 28; i++) mm[i] += __shfl_xor(mm[i], d);
  }
  if (t == 0) {
    #pragma unroll
    for (int i = 0; i < 28; i++) part0[blockIdx.x * 28 + i] = mm[i];
  }
}

// ---------------------------------------------------------------------------
// COOP1: finalize0 (local) -> stats1 -> grid.sync -> finalize1 (local) -> pool
// grid 256 x 256, 1 block/CU.
// ---------------------------------------------------------------------------
__global__ __launch_bounds__(256) void coop1_kernel(
    const float* __restrict__ g0buf, const float* __restrict__ g1buf,
    const int* __restrict__ cnt, const float* __restrict__ part0,
    float* __restrict__ part1,
    const float* __restrict__ W0s0, const float* __restrict__ gm0s0, const float* __restrict__ bt0s0,
    const float* __restrict__ W0s1, const float* __restrict__ gm0s1, const float* __restrict__ bt0s1,
    const float* __restrict__ W1s0, const float* __restrict__ gm1s0, const float* __restrict__ bt1s0,
    const float* __restrict__ W1s1, const float* __restrict__ gm1s1, const float* __restrict__ bt1s1,
    float* __restrict__ feats)
{
  cg::grid_group grid = cg::this_grid();
  __shared__ float sW0a[64], sW0b[64], sW1a[256], sW1b[512], sP[160];
  __shared__ float S0[28], S1[96];
  __shared__ float red[16][96];
  const int t = threadIdx.x;

  // weights -> LDS
  if (t < 64) { sW0a[t] = W0s0[t]; sW0b[t] = W0s1[t]; }
  sW1a[t]       = W1s0[t];
  sW1b[t]       = W1s1[t];
  sW1b[t + 256] = W1s1[t + 256];
  for (int i = t; i < 16 * 96; i += 256) ((float*)red)[i] = 0.f;

  // ---- phase F0: BN0 params from part0 (redundant per block) ----
  if (t < 28) {
    float v = 0.f;
    for (int r = 0; r < QBLOCKS; r++) v += part0[r * 28 + t];
    S0[t] = v;
  }
  __syncthreads();
  if (t < 32) {
    const int s = t >> 4, c = t & 15;
    const float* W  = s ? sW0b : sW0a;
    const float* G  = s ? gm0s1 : gm0s0;
    const float* Bt = s ? bt0s1 : bt0s0;
    const float* Sx = S0 + s * 14;
    const float w0 = W[c*4+0], w1 = W[c*4+1];
    const float w2 = W[c*4+2], w3 = W[c*4+3];
    const float inv = 1.0f / MSAMP;
    const float mean = (w0*Sx[0] + w1*Sx[1] + w2*Sx[2] + w3*Sx[3]) * inv;
    float e2 = w0*w0*Sx[4] + 2.f*w0*w1*Sx[5] + 2.f*w0*w2*Sx[6] + 2.f*w0*w3*Sx[7]
             + w1*w1*Sx[8] + 2.f*w1*w2*Sx[9] + 2.f*w1*w3*Sx[10]
             + w2*w2*Sx[11] + 2.f*w2*w3*Sx[12] + w3*w3*Sx[13];
    e2 *= inv;
    const float var = e2 - mean * mean;
    const float A = G[c] / sqrtf(var + 1e-5f);
    sP[s*32 + c]      = A;
    sP[s*32 + 16 + c] = Bt[c] - mean * A;
  }
  __syncthreads();

  // ---- phase S1: BN1 stats over this block's 256 slots ----
  {
    const int slot = blockIdx.x * 256 + t;
    const int wave = t >> 6, lane = t & 63;
    const int grp  = (wave << 2) | (lane >> 4);
    const bool leader = (lane & 15) == 0;
    float a1[16];
    {  // scale 0
      const float4 x = *(const float4*)(g0buf + (size_t)slot * 4);
      #pragma unroll
      for (int c = 0; c < 16; c++) {
        const float h = sW0a[c*4+0]*x.x + sW0a[c*4+1]*x.y + sW0a[c*4+2]*x.z + sW0a[c*4+3]*x.w;
        a1[c] = fmaxf(fmaf(sP[c], h, sP[16+c]), 0.f);
      }
      #pragma unroll
      for (int o = 0; o < 16; o++) {
        float h2 = 0.f;
        #pragma unroll
        for (int c = 0; c < 16; c++) h2 = fmaf(sW1a[o*16+c], a1[c], h2);
        float s = h2, q = h2 * h2;
        #pragma unroll
        for (int d = 1; d < 16; d <<= 1) { s += __shfl_xor(s, d); q += __shfl_xor(q, d); }
        if (leader) { red[grp][o] += s; red[grp][16+o] += q; }
      }
    }
    {  // scale 1
      const float4 x = *(const float4*)(g1buf + (size_t)slot * 4);
      #pragma unroll
      for (int c = 0; c < 16; c++) {
        const float h = sW0b[c*4+0]*x.x + sW0b[c*4+1]*x.y + sW0b[c*4+2]*x.z + sW0b[c*4+3]*x.w;
        a1[c] = fmaxf(fmaf(sP[32+c], h, sP[48+c]), 0.f);
      }
      #pragma unroll
      for (int o = 0; o < 32; o++) {
        float h2 = 0.f;
        #pragma unroll
        for (int c = 0; c < 16; c++) h2 = fmaf(sW1b[o*16+c], a1[c], h2);
        float s = h2, q = h2 * h2;
        #pragma unroll
        for (int d = 1; d < 16; d <<= 1) { s += __shfl_xor(s, d); q += __shfl_xor(q, d); }
        if (leader) { red[grp][32+o] += s; red[grp][64+o] += q; }
      }
    }
  }
  __syncthreads();
  if (t < 96) {
    float s = 0.f;
    #pragma unroll
    for (int g = 0; g < 16; g++) s += red[g][t];
    part1[blockIdx.x * 96 + t] = s;
  }

  grid.sync();

  // ---- phase F1: BN1 params (redundant per block) ----
  if (t < 96) {
    float s0 = 0.f, s1 = 0.f, s2 = 0.f, s3 = 0.f;
    for (int r = 0; r < 256; r += 4) {
      s0 += part1[(r + 0) * 96 + t];
      s1 += part1[(r + 1) * 96 + t];
      s2 += part1[(r + 2) * 96 + t];
      s3 += part1[(r + 3) * 96 + t];
    }
    S1[t] = (s0 + s1) + (s2 + s3);
  }
  __syncthreads();
  if (t < 48) {
    float sum, sq, G, Bv; int oA, oB;
    if (t < 16) { sum = S1[t];    sq = S1[16+t]; G = gm1s0[t]; Bv = bt1s0[t]; oA = 64+t;  oB = 80+t; }
    else { const int c = t - 16; sum = S1[32+c]; sq = S1[64+c]; G = gm1s1[c]; Bv = bt1s1[c]; oA = 96+c; oB = 128+c; }
    const float mean = sum / MSAMP;
    const float var  = sq / MSAMP - mean * mean;
    const float A = G / sqrtf(var + 1e-5f);
    sP[oA] = A;
    sP[oB] = Bv - mean * A;
  }
  __syncthreads();

  // ---- phase P: MLP + max-pool, 16 keypoints/block ----
  {
    const int lkp = t >> 4, slot = t & 15;
    const int bk = blockIdx.x * 16 + lkp;
    const size_t si = (size_t)bk * 16 + slot;
    float a1[16], a2s0[16], a2s1[32];
    {
      const float4 x = *(const float4*)(g0buf + si * 4);
      #pragma unroll
      for (int c = 0; c < 16; c++) {
        const float h = sW0a[c*4+0]*x.x + sW0a[c*4+1]*x.y + sW0a[c*4+2]*x.z + sW0a[c*4+3]*x.w;
        a1[c] = fmaxf(fmaf(sP[c], h, sP[16+c]), 0.f);
      }
      #pragma unroll
      for (int o = 0; o < 16; o++) {
        float h2 = 0.f;
        #pragma unroll
        for (int c = 0; c < 16; c++) h2 = fmaf(sW1a[o*16+c], a1[c], h2);
        a2s0[o] = fmaxf(fmaf(sP[64+o], h2, sP[80+o]), 0.f);
      }
    }
    {
      const float4 x = *(const float4*)(g1buf + si * 4);
      #pragma unroll
      for (int c = 0; c < 16; c++) {
        const float h = sW0b[c*4+0]*x.x + sW0b[c*4+1]*x.y + sW0b[c*4+2]*x.z + sW0b[c*4+3]*x.w;
        a1[c] = fmaxf(fmaf(sP[32+c], h, sP[48+c]), 0.f);
      }
      #pragma unroll
      for (int o = 0; o < 32; o++) {
        float h2 = 0.f;
        #pragma unroll
        for (int c = 0; c < 16; c++) h2 = fmaf(sW1b[o*16+c], a1[c], h2);
        a2s1[o] = fmaxf(fmaf(sP[96+o], h2, sP[128+o]), 0.f);
      }
    }
    #pragma unroll
    for (int d = 1; d < 16; d <<= 1) {
      #pragma unroll
      for (int o = 0; o < 16; o++) a2s0[o] = fmaxf(a2s0[o], __shfl_xor(a2s0[o], d));
      #pragma unroll
      for (int o = 0; o < 32; o++) a2s1[o] = fmaxf(a2s1[o], __shfl_xor(a2s1[o], d));
    }
    if (slot == 0) {
      const int c0 = cnt[bk], c1 = cnt[NBK + bk];
      float* outp = feats + (size_t)bk * 304 + 256;
      #pragma unroll
      for (int o = 0; o < 16; o++) outp[o] = c0 ? a2s0[o] : 0.f;
      #pragma unroll
      for (int o = 0; o < 32; o++) outp[16 + o] = c1 ? a2s1[o] : 0.f;
    }
  }
}

// ---------------------------------------------------------------------------
// COOP2: fused GEMM (acc in regs) -> grid.sync -> final BN+relu -> out
// grid 256 x 128.
// ---------------------------------------------------------------------------
__global__ __launch_bounds__(128) void coop2_kernel(
    const float* __restrict__ feats, const float* __restrict__ Wf,
    const float* __restrict__ gf, const float* __restrict__ bfp,
    float* __restrict__ part2, float* __restrict__ out)
{
  cg::grid_group grid = cg::this_grid();
  __shared__ __align__(16) float sF[16 * 304];
  const int t = threadIdx.x;
  const int r0 = blockIdx.x * 16;
  for (int i = t; i < 16 * 304; i += 128) sF[i] = feats[(size_t)r0 * 304 + i];
  __syncthreads();
  float acc[16];
  #pragma unroll
  for (int r = 0; r < 16; r++) acc[r] = 0.f;
  const float* wrow = Wf + (size_t)t * 304;
  for (int j4 = 0; j4 < 76; j4++) {
    const float4 w = *(const float4*)(wrow + j4 * 4);
    #pragma unroll
    for (int r = 0; r < 16; r++) {
      const float4 f = *(const float4*)(sF + r * 304 + j4 * 4);
      acc[r] = fmaf(w.x, f.x, acc[r]);
      acc[r] = fmaf(w.y, f.y, acc[r]);
      acc[r] = fmaf(w.z, f.z, acc[r]);
      acc[r] = fmaf(w.w, f.w, acc[r]);
    }
  }
  float s = 0.f, q = 0.f;
  #pragma unroll
  for (int r = 0; r < 16; r++) {
    s += acc[r];
    q = fmaf(acc[r], acc[r], q);
  }
  part2[blockIdx.x * 256 + t]       = s;
  part2[blockIdx.x * 256 + 128 + t] = q;

  grid.sync();

  float ss = 0.f, qq = 0.f;
  for (int r = 0; r < 256; r++) {
    ss += part2[r * 256 + t];
    qq += part2[r * 256 + 128 + t];
  }
  const float mean = ss / MROW;
  const float var  = qq / MROW - mean * mean;
  const float A = gf[t] / sqrtf(var + 1e-5f);
  const float Bv = bfp[t] - mean * A;
  #pragma unroll
  for (int r = 0; r < 16; r++) {
    out[(size_t)(r0 + r) * 128 + t] = fmaxf(fmaf(acc[r], A, Bv), 0.f);
  }
}

// ---------------------------------------------------------------------------
extern "C" void kernel_launch(void* const* d_in, const int* in_sizes, int n_in,
                              void* d_out, int out_size, void* d_ws, size_t ws_size,
                              hipStream_t stream)
{
  const float* kp    = (const float*)d_in[0];
  const float* pts   = (const float*)d_in[1];
  const float* pfeat = (const float*)d_in[2];
  const float* bev   = (const float*)d_in[3];
  const int*   strd  = (const int*)d_in[4];
  const float* W0s0  = (const float*)d_in[5];
  const float* g0s0  = (const float*)d_in[6];
  const float* b0s0  = (const float*)d_in[7];
  const float* W1s0  = (const float*)d_in[8];
  const float* g1s0  = (const float*)d_in[9];
  const float* b1s0  = (const float*)d_in[10];
  const float* W0s1  = (const float*)d_in[11];
  const float* g0s1  = (const float*)d_in[12];
  const float* b0s1  = (const float*)d_in[13];
  const float* W1s1  = (const float*)d_in[14];
  const float* g1s1  = (const float*)d_in[15];
  const float* b1s1  = (const float*)d_in[16];
  const float* Wf    = (const float*)d_in[17];
  const float* gf    = (const float*)d_in[18];
  const float* bfv   = (const float*)d_in[19];

  float* w      = (float*)d_ws;
  float* g0buf  = w;                    // 262144
  float* g1buf  = w + 262144;           // 262144
  float* feats  = w + 524288;           // 4096*304 = 1245184
  float* part0  = w + 1769472;          // 64*28 (reserve 4096)
  float* part1  = w + 1773568;          // 256*96 = 24576
  float* part2  = w + 1798144;          // 256*256 = 65536
  int*   cnt       = (int*)(w + 1863680);   // 8192 ints
  int*   bin_start = (int*)(w + 1871872);   // 9216
  int*   bin_fill  = (int*)(w + 1881088);   // 9216
  int*   sidx      = (int*)(w + 1890304);   // 32768
  float4* sorted   = (float4*)(w + 1923072);// 32768 float4 (16B aligned)
  float* outp   = (float*)d_out;

  hipLaunchKernelGGL(bev_kernel,     dim3(4096), dim3(256), 0, stream, kp, bev, strd, feats);
  hipLaunchKernelGGL(build_kernel,   dim3(2),    dim3(256), 0, stream, pts, bin_start, bin_fill);
  hipLaunchKernelGGL(scatter_kernel, dim3(128),  dim3(256), 0, stream, pts, pfeat, bin_fill, sorted, sidx);
  hipLaunchKernelGGL(query_kernel,   dim3(QBLOCKS), dim3(64), 0, stream, kp, bin_start, sorted, sidx, g0buf, g1buf, cnt, part0);

  {
    void* args[] = {
      (void*)&g0buf, (void*)&g1buf, (void*)&cnt, (void*)&part0, (void*)&part1,
      (void*)&W0s0, (void*)&g0s0, (void*)&b0s0,
      (void*)&W0s1, (void*)&g0s1, (void*)&b0s1,
      (void*)&W1s0, (void*)&g1s0, (void*)&b1s0,
      (void*)&W1s1, (void*)&g1s1, (void*)&b1s1,
      (void*)&feats
    };
    hipLaunchCooperativeKernel((const void*)coop1_kernel, dim3(256), dim3(256), args, 0, stream);
  }
  {
    void* args[] = {
      (void*)&feats, (void*)&Wf, (void*)&gf, (void*)&bfv,
      (void*)&part2, (void*)&outp
    };
    hipLaunchCooperativeKernel((const void*)coop2_kernel, dim3(256), dim3(128), args, 0, stream);
  }
}

// Round 7
// 233.418 us; speedup vs baseline: 1.5114x; 1.5114x over previous
//
#include <hip/hip_runtime.h>
#include <hip/hip_bf16.h>

#define NB    2
#define NK    2048
#define NPTS  16384
#define NBK   4096            // NB*NK
#define MSAMP 65536.0f        // NBK*16 samples per scale for BN0/BN1
#define MROW  4096.0f         // rows for final BN

// ---------------------------------------------------------------------------
// A: mega-kernel. Blocks 0..1023: ball-query grouping (round-4 verified code).
//    Blocks 1024..5119: BEV bilinear interp. Independent workloads co-resident.
// ---------------------------------------------------------------------------
__global__ __launch_bounds__(256) void mega_kernel(
    const float* __restrict__ kp, const float* __restrict__ pts,
    const float* __restrict__ pfeat, const float* __restrict__ bev,
    const int* __restrict__ stridep,
    float* __restrict__ g0buf, float* __restrict__ g1buf,
    int* __restrict__ cnt, float* __restrict__ part0,
    float* __restrict__ feats)
{
  __shared__ float sxyz[3072];          // 1024 points * 3 (point-major)
  __shared__ float sfeat[1024];
  __shared__ float slots[4][2][16][4];
  __shared__ float bred[4][28];
  const int t = threadIdx.x;

  if (blockIdx.x >= 1024) {
    // ---- BEV role ----
    const int bk = blockIdx.x - 1024;    // 0..4095
    const int c  = t;                    // channel 0..255
    const int b  = bk >> 11;
    const float st = (float)(*stridep);
    const float x = (kp[bk*3+0] - (-70.4f)) / 0.1f / st;
    const float y = (kp[bk*3+1] - (-40.0f)) / 0.1f / st;
    const int xf = (int)floorf(x), yf = (int)floorf(y);
    const int x0 = min(max(xf, 0), 175), x1 = min(max(xf + 1, 0), 175);
    const int y0 = min(max(yf, 0), 99),  y1 = min(max(yf + 1, 0), 99);
    const float x0f = (float)x0, x1f = (float)x1, y0f = (float)y0, y1f = (float)y1;
    const float wa = (x1f - x) * (y1f - y);
    const float wb = (x1f - x) * (y - y0f);
    const float wc = (x - x0f) * (y1f - y);
    const float wd = (x - x0f) * (y - y0f);
    const size_t base = ((size_t)b * 256 + c) * 17600;  // 100*176
    const float Ia = bev[base + y0 * 176 + x0];
    const float Ib = bev[base + y1 * 176 + x0];
    const float Ic = bev[base + y0 * 176 + x1];
    const float Id = bev[base + y1 * 176 + x1];
    feats[(size_t)bk * 304 + c] = Ia * wa + Ib * wb + Ic * wc + Id * wd;
    return;
  }

  // ---- GROUP role (LDS-tiled ball query, round-4 verified) ----
  const int gb = blockIdx.x;            // 0..1023
  const int wave = t >> 6;
  const int lane = t & 63;
  const int bk = gb * 4 + wave;
  const int b  = gb >> 9;               // 512 blocks per batch
  const float kx = kp[bk*3+0];
  const float ky = kp[bk*3+1];
  const float kz = kp[bk*3+2];
  const float* px = pts   + (size_t)b * NPTS * 3;
  const float* pf = pfeat + (size_t)b * NPTS;
  int c0 = 0, c1 = 0;
  bool done = false;
  const unsigned long long below = (1ull << lane) - 1ull;

  for (int tile = 0; tile < 16; tile++) {
    __syncthreads();
    {
      const float4* gsrc = (const float4*)(px + tile * 3072);
      float4* ldst = (float4*)sxyz;
      ldst[t]       = gsrc[t];
      ldst[t + 256] = gsrc[t + 256];
      ldst[t + 512] = gsrc[t + 512];
      #pragma unroll
      for (int i = 0; i < 4; i++) sfeat[t + i * 256] = pf[tile * 1024 + t + i * 256];
    }
    __syncthreads();
    if (!done) {
      for (int inner = 0; inner < 16; inner++) {
        const int pp = inner * 64 + lane;
        const float x = sxyz[pp*3+0];
        const float y = sxyz[pp*3+1];
        const float z = sxyz[pp*3+2];
        const float dx = x - kx, dy = y - ky, dz = z - kz;
        const float d2 = dx*dx + dy*dy + dz*dz;
        const bool w0 = d2 < 0.16f;   // 0.4^2
        const bool w1 = d2 < 0.64f;   // 0.8^2
        const unsigned long long m1 = __ballot(w1);
        if (m1) {
          const unsigned long long m0 = __ballot(w0);
          const float f = sfeat[pp];
          const int o0 = c0 + __popcll(m0 & below);
          if (w0 && o0 < 16) {
            slots[wave][0][o0][0] = dx; slots[wave][0][o0][1] = dy;
            slots[wave][0][o0][2] = dz; slots[wave][0][o0][3] = f;
          }
          const int o1 = c1 + __popcll(m1 & below);
          if (w1 && o1 < 16) {
            slots[wave][1][o1][0] = dx; slots[wave][1][o1][1] = dy;
            slots[wave][1][o1][2] = dz; slots[wave][1][o1][3] = f;
          }
          c0 += __popcll(m0);
          c1 += __popcll(m1);
          if (c0 >= 16) { done = true; break; }
        }
      }
    }
  }
  __syncthreads();

  if (lane < 32) {
    const int s  = (lane >> 4) & 1;
    const int sl = lane & 15;
    const int cs = s ? c1 : c0;
    if (cs == 0) {
      slots[wave][s][sl][0] = 0.f; slots[wave][s][sl][1] = 0.f;
      slots[wave][s][sl][2] = 0.f; slots[wave][s][sl][3] = 0.f;
    } else if (sl >= cs) {
      slots[wave][s][sl][0] = slots[wave][s][0][0];
      slots[wave][s][sl][1] = slots[wave][s][0][1];
      slots[wave][s][sl][2] = slots[wave][s][0][2];
      slots[wave][s][sl][3] = slots[wave][s][0][3];
    }
  }

  g0buf[(size_t)bk * 64 + lane] = slots[wave][0][lane >> 2][lane & 3];
  g1buf[(size_t)bk * 64 + lane] = slots[wave][1][lane >> 2][lane & 3];
  if (lane == 0) { cnt[bk] = c0; cnt[NBK + bk] = c1; }

  float v[14];
  {
    float x0 = 0.f, x1 = 0.f, x2 = 0.f, x3 = 0.f;
    if (lane < 32) {
      const int s  = (lane >> 4) & 1;
      const int sl = lane & 15;
      x0 = slots[wave][s][sl][0]; x1 = slots[wave][s][sl][1];
      x2 = slots[wave][s][sl][2]; x3 = slots[wave][s][sl][3];
    }
    v[0] = x0; v[1] = x1; v[2] = x2; v[3] = x3;
    v[4] = x0*x0; v[5] = x0*x1; v[6]  = x0*x2; v[7]  = x0*x3;
    v[8] = x1*x1; v[9] = x1*x2; v[10] = x1*x3;
    v[11] = x2*x2; v[12] = x2*x3; v[13] = x3*x3;
  }
  #pragma unroll
  for (int d = 1; d < 16; d <<= 1) {
    #pragma unroll
    for (int i = 0; i < 14; i++) v[i] += __shfl_xor(v[i], d);
  }
  if (lane == 0 || lane == 16) {
    float* dst = &bred[wave][(lane >> 4) * 14];
    #pragma unroll
    for (int i = 0; i < 14; i++) dst[i] = v[i];
  }
  __syncthreads();
  if (t < 28) {
    part0[gb * 28 + t] = bred[0][t] + bred[1][t] + bred[2][t] + bred[3][t];
  }
}

// ---------------------------------------------------------------------------
// helper: compute BN0 params (sP[0:64]) from S0[28] sums — runs in-block
// ---------------------------------------------------------------------------
__device__ __forceinline__ void bn0_params(
    int t, const float* S0, const float* sW0a, const float* sW0b,
    const float* gm0s0, const float* bt0s0,
    const float* gm0s1, const float* bt0s1, float* sP)
{
  if (t < 32) {
    const int s = t >> 4, c = t & 15;
    const float* W  = s ? sW0b : sW0a;
    const float* G  = s ? gm0s1 : gm0s0;
    const float* Bt = s ? bt0s1 : bt0s0;
    const float* Sx = S0 + s * 14;
    const float w0 = W[c*4+0], w1 = W[c*4+1];
    const float w2 = W[c*4+2], w3 = W[c*4+3];
    const float inv = 1.0f / MSAMP;
    const float mean = (w0*Sx[0] + w1*Sx[1] + w2*Sx[2] + w3*Sx[3]) * inv;
    float e2 = w0*w0*Sx[4] + 2.f*w0*w1*Sx[5] + 2.f*w0*w2*Sx[6] + 2.f*w0*w3*Sx[7]
             + w1*w1*Sx[8] + 2.f*w1*w2*Sx[9] + 2.f*w1*w3*Sx[10]
             + w2*w2*Sx[11] + 2.f*w2*w3*Sx[12] + w3*w3*Sx[13];
    e2 *= inv;
    const float var = e2 - mean * mean;
    const float A = G[c] / sqrtf(var + 1e-5f);
    sP[s*32 + c]      = A;
    sP[s*32 + 16 + c] = Bt[c] - mean * A;
  }
}

// ---------------------------------------------------------------------------
// B: BN1 stats (local BN0 finalize + per-slot MLP layer01 + sum/sumsq).
// grid 256 x 256. part1[block][96].
// ---------------------------------------------------------------------------
__global__ __launch_bounds__(256) void stats1_kernel(
    const float* __restrict__ g0buf, const float* __restrict__ g1buf,
    const float* __restrict__ part0,
    const float* __restrict__ W0s0, const float* __restrict__ gm0s0, const float* __restrict__ bt0s0,
    const float* __restrict__ W0s1, const float* __restrict__ gm0s1, const float* __restrict__ bt0s1,
    const float* __restrict__ W1s0, const float* __restrict__ W1s1,
    float* __restrict__ part1)
{
  __shared__ float sW0a[64], sW0b[64], sW1a[256], sW1b[512], sP[64];
  __shared__ float tmp0[8][28], S0[28];
  __shared__ float red[16][96];
  const int t = threadIdx.x;
  if (t < 64) { sW0a[t] = W0s0[t]; sW0b[t] = W0s1[t]; }
  sW1a[t]       = W1s0[t];
  sW1b[t]       = W1s1[t];
  sW1b[t + 256] = W1s1[t + 256];
  for (int i = t; i < 16 * 96; i += 256) ((float*)red)[i] = 0.f;
  // local finalize0: sum part0[1024][28]
  if (t < 224) {
    const int seg = t / 28, col = t % 28;
    float s = 0.f;
    for (int r = seg * 128; r < seg * 128 + 128; r++) s += part0[r * 28 + col];
    tmp0[seg][col] = s;
  }
  __syncthreads();
  if (t < 28) {
    float s = 0.f;
    #pragma unroll
    for (int g = 0; g < 8; g++) s += tmp0[g][t];
    S0[t] = s;
  }
  __syncthreads();
  bn0_params(t, S0, sW0a, sW0b, gm0s0, bt0s0, gm0s1, bt0s1, sP);
  __syncthreads();

  const int slot = blockIdx.x * 256 + t;
  const int wave = t >> 6, lane = t & 63;
  const int grp  = (wave << 2) | (lane >> 4);
  const bool leader = (lane & 15) == 0;

  float a1[16];
  {  // scale 0
    const float4 x = *(const float4*)(g0buf + (size_t)slot * 4);
    #pragma unroll
    for (int c = 0; c < 16; c++) {
      const float h = sW0a[c*4+0]*x.x + sW0a[c*4+1]*x.y + sW0a[c*4+2]*x.z + sW0a[c*4+3]*x.w;
      a1[c] = fmaxf(fmaf(sP[c], h, sP[16+c]), 0.f);
    }
    #pragma unroll
    for (int o = 0; o < 16; o++) {
      float h2 = 0.f;
      #pragma unroll
      for (int c = 0; c < 16; c++) h2 = fmaf(sW1a[o*16+c], a1[c], h2);
      float s = h2, q = h2 * h2;
      #pragma unroll
      for (int d = 1; d < 16; d <<= 1) { s += __shfl_xor(s, d); q += __shfl_xor(q, d); }
      if (leader) { red[grp][o] += s; red[grp][16+o] += q; }
    }
  }
  {  // scale 1
    const float4 x = *(const float4*)(g1buf + (size_t)slot * 4);
    #pragma unroll
    for (int c = 0; c < 16; c++) {
      const float h = sW0b[c*4+0]*x.x + sW0b[c*4+1]*x.y + sW0b[c*4+2]*x.z + sW0b[c*4+3]*x.w;
      a1[c] = fmaxf(fmaf(sP[32+c], h, sP[48+c]), 0.f);
    }
    #pragma unroll
    for (int o = 0; o < 32; o++) {
      float h2 = 0.f;
      #pragma unroll
      for (int c = 0; c < 16; c++) h2 = fmaf(sW1b[o*16+c], a1[c], h2);
      float s = h2, q = h2 * h2;
      #pragma unroll
      for (int d = 1; d < 16; d <<= 1) { s += __shfl_xor(s, d); q += __shfl_xor(q, d); }
      if (leader) { red[grp][32+o] += s; red[grp][64+o] += q; }
    }
  }
  __syncthreads();
  if (t < 96) {
    float s = 0.f;
    #pragma unroll
    for (int g = 0; g < 16; g++) s += red[g][t];
    part1[blockIdx.x * 96 + t] = s;
  }
}

// ---------------------------------------------------------------------------
// C: pool (local finalize0 + finalize1 + MLP + max-pool). grid 256 x 256.
// ---------------------------------------------------------------------------
__global__ __launch_bounds__(256) void pool_kernel(
    const float* __restrict__ g0buf, const float* __restrict__ g1buf,
    const int* __restrict__ cnt,
    const float* __restrict__ part0, const float* __restrict__ part1,
    const float* __restrict__ W0s0, const float* __restrict__ gm0s0, const float* __restrict__ bt0s0,
    const float* __restrict__ W0s1, const float* __restrict__ gm0s1, const float* __restrict__ bt0s1,
    const float* __restrict__ W1s0, const float* __restrict__ gm1s0, const float* __restrict__ bt1s0,
    const float* __restrict__ W1s1, const float* __restrict__ gm1s1, const float* __restrict__ bt1s1,
    float* __restrict__ feats)
{
  __shared__ float sW0a[64], sW0b[64], sW1a[256], sW1b[512], sP[160];
  __shared__ float tmp0[8][28], S0[28];
  __shared__ float tmp1[2][96], S1[96];
  const int t = threadIdx.x;
  if (t < 64)  { sW0a[t] = W0s0[t]; sW0b[t] = W0s1[t]; }
  sW1a[t]       = W1s0[t];
  sW1b[t]       = W1s1[t];
  sW1b[t + 256] = W1s1[t + 256];
  // local finalize0
  if (t < 224) {
    const int seg = t / 28, col = t % 28;
    float s = 0.f;
    for (int r = seg * 128; r < seg * 128 + 128; r++) s += part0[r * 28 + col];
    tmp0[seg][col] = s;
  }
  // local finalize1 sums (part1: 256 rows x 96)
  __syncthreads();
  if (t < 28) {
    float s = 0.f;
    #pragma unroll
    for (int g = 0; g < 8; g++) s += tmp0[g][t];
    S0[t] = s;
  }
  if (t >= 32 && t < 224) {
    const int tt = t - 32;
    const int seg = tt / 96, col = tt % 96;
    float s = 0.f;
    for (int r = seg * 128; r < seg * 128 + 128; r++) s += part1[r * 96 + col];
    tmp1[seg][col] = s;
  }
  __syncthreads();
  bn0_params(t, S0, sW0a, sW0b, gm0s0, bt0s0, gm0s1, bt0s1, sP);
  if (t >= 64 && t < 160) {
    const int c = t - 64;
    S1[c] = tmp1[0][c] + tmp1[1][c];
  }
  __syncthreads();
  if (t < 48) {
    float sum, sq, G, Bv; int oA, oB;
    if (t < 16) { sum = S1[t];    sq = S1[16+t]; G = gm1s0[t]; Bv = bt1s0[t]; oA = 64+t;  oB = 80+t; }
    else { const int c = t - 16; sum = S1[32+c]; sq = S1[64+c]; G = gm1s1[c]; Bv = bt1s1[c]; oA = 96+c; oB = 128+c; }
    const float mean = sum / MSAMP;
    const float var  = sq / MSAMP - mean * mean;
    const float A = G / sqrtf(var + 1e-5f);
    sP[oA] = A;
    sP[oB] = Bv - mean * A;
  }
  __syncthreads();

  const int lkp = t >> 4, slot = t & 15;
  const int bk = blockIdx.x * 16 + lkp;
  const size_t si = (size_t)bk * 16 + slot;
  float a1[16], a2s0[16], a2s1[32];
  {
    const float4 x = *(const float4*)(g0buf + si * 4);
    #pragma unroll
    for (int c = 0; c < 16; c++) {
      const float h = sW0a[c*4+0]*x.x + sW0a[c*4+1]*x.y + sW0a[c*4+2]*x.z + sW0a[c*4+3]*x.w;
      a1[c] = fmaxf(fmaf(sP[c], h, sP[16+c]), 0.f);
    }
    #pragma unroll
    for (int o = 0; o < 16; o++) {
      float h2 = 0.f;
      #pragma unroll
      for (int c = 0; c < 16; c++) h2 = fmaf(sW1a[o*16+c], a1[c], h2);
      a2s0[o] = fmaxf(fmaf(sP[64+o], h2, sP[80+o]), 0.f);
    }
  }
  {
    const float4 x = *(const float4*)(g1buf + si * 4);
    #pragma unroll
    for (int c = 0; c < 16; c++) {
      const float h = sW0b[c*4+0]*x.x + sW0b[c*4+1]*x.y + sW0b[c*4+2]*x.z + sW0b[c*4+3]*x.w;
      a1[c] = fmaxf(fmaf(sP[32+c], h, sP[48+c]), 0.f);
    }
    #pragma unroll
    for (int o = 0; o < 32; o++) {
      float h2 = 0.f;
      #pragma unroll
      for (int c = 0; c < 16; c++) h2 = fmaf(sW1b[o*16+c], a1[c], h2);
      a2s1[o] = fmaxf(fmaf(sP[96+o], h2, sP[128+o]), 0.f);
    }
  }
  #pragma unroll
  for (int d = 1; d < 16; d <<= 1) {
    #pragma unroll
    for (int o = 0; o < 16; o++) a2s0[o] = fmaxf(a2s0[o], __shfl_xor(a2s0[o], d));
    #pragma unroll
    for (int o = 0; o < 32; o++) a2s1[o] = fmaxf(a2s1[o], __shfl_xor(a2s1[o], d));
  }
  if (slot == 0) {
    const int c0 = cnt[bk], c1 = cnt[NBK + bk];
    float* outp = feats + (size_t)bk * 304 + 256;
    #pragma unroll
    for (int o = 0; o < 16; o++) outp[o] = c0 ? a2s0[o] : 0.f;
    #pragma unroll
    for (int o = 0; o < 32; o++) outp[16 + o] = c1 ? a2s1[o] : 0.f;
  }
}

// ---------------------------------------------------------------------------
// D: fused = feats(4096x304) @ Wf^T(304x128) + per-column partial stats.
// 8 rows per block, 512 blocks x 128 threads (2 blocks/CU).
// ---------------------------------------------------------------------------
__global__ __launch_bounds__(128) void fused_kernel(
    const float* __restrict__ feats, const float* __restrict__ Wf,
    float* __restrict__ fused, float* __restrict__ part2)
{
  __shared__ __align__(16) float sF[8 * 304];
  const int t = threadIdx.x;
  const int r0 = blockIdx.x * 8;
  for (int i = t; i < 8 * 304; i += 128) sF[i] = feats[(size_t)r0 * 304 + i];
  __syncthreads();
  float acc[8];
  #pragma unroll
  for (int r = 0; r < 8; r++) acc[r] = 0.f;
  const float* wrow = Wf + (size_t)t * 304;
  for (int j4 = 0; j4 < 76; j4++) {
    const float4 w = *(const float4*)(wrow + j4 * 4);
    #pragma unroll
    for (int r = 0; r < 8; r++) {
      const float4 f = *(const float4*)(sF + r * 304 + j4 * 4);
      acc[r] = fmaf(w.x, f.x, acc[r]);
      acc[r] = fmaf(w.y, f.y, acc[r]);
      acc[r] = fmaf(w.z, f.z, acc[r]);
      acc[r] = fmaf(w.w, f.w, acc[r]);
    }
  }
  float s = 0.f, q = 0.f;
  #pragma unroll
  for (int r = 0; r < 8; r++) {
    fused[(size_t)(r0 + r) * 128 + t] = acc[r];
    s += acc[r];
    q = fmaf(acc[r], acc[r], q);
  }
  part2[blockIdx.x * 256 + t]       = s;
  part2[blockIdx.x * 256 + 128 + t] = q;
}

// ---------------------------------------------------------------------------
// E: out (local finalize2 + BN + relu). 128 blocks x 256 threads,
// 16 elems (4 float4) per thread.
// ---------------------------------------------------------------------------
__global__ __launch_bounds__(256) void out_kernel(
    const float* __restrict__ fused, const float* __restrict__ part2,
    const float* __restrict__ gf, const float* __restrict__ bfp,
    float* __restrict__ out)
{
  __shared__ float sA[128], sB[128];
  __shared__ float tmp[2][128];
  const int t = threadIdx.x;
  // local finalize2: part2 has 512 rows x 256 (s at col c, q at 128+c)
  {
    const int c = t & 127, which = t >> 7;
    float s = 0.f;
    for (int r = 0; r < 512; r++) s += part2[r * 256 + which * 128 + c];
    tmp[which][c] = s;
  }
  __syncthreads();
  if (t < 128) {
    const float mean = tmp[0][t] / MROW;
    const float var  = tmp[1][t] / MROW - mean * mean;
    const float A = gf[t] / sqrtf(var + 1e-5f);
    sA[t] = A;
    sB[t] = bfp[t] - mean * A;
  }
  __syncthreads();
  #pragma unroll
  for (int k = 0; k < 4; k++) {
    const int f4 = blockIdx.x * 1024 + k * 256 + t;   // 0..131071
    const int i = f4 * 4;
    const float4 v = *(const float4*)(fused + i);
    const int c = i & 127;
    float4 o;
    o.x = fmaxf(fmaf(v.x, sA[c+0], sB[c+0]), 0.f);
    o.y = fmaxf(fmaf(v.y, sA[c+1], sB[c+1]), 0.f);
    o.z = fmaxf(fmaf(v.z, sA[c+2], sB[c+2]), 0.f);
    o.w = fmaxf(fmaf(v.w, sA[c+3], sB[c+3]), 0.f);
    *(float4*)(out + i) = o;
  }
}

// ---------------------------------------------------------------------------
extern "C" void kernel_launch(void* const* d_in, const int* in_sizes, int n_in,
                              void* d_out, int out_size, void* d_ws, size_t ws_size,
                              hipStream_t stream)
{
  const float* kp    = (const float*)d_in[0];
  const float* pts   = (const float*)d_in[1];
  const float* pfeat = (const float*)d_in[2];
  const float* bev   = (const float*)d_in[3];
  const int*   strd  = (const int*)d_in[4];
  const float* W0s0  = (const float*)d_in[5];
  const float* g0s0  = (const float*)d_in[6];
  const float* b0s0  = (const float*)d_in[7];
  const float* W1s0  = (const float*)d_in[8];
  const float* g1s0  = (const float*)d_in[9];
  const float* b1s0  = (const float*)d_in[10];
  const float* W0s1  = (const float*)d_in[11];
  const float* g0s1  = (const float*)d_in[12];
  const float* b0s1  = (const float*)d_in[13];
  const float* W1s1  = (const float*)d_in[14];
  const float* g1s1  = (const float*)d_in[15];
  const float* b1s1  = (const float*)d_in[16];
  const float* Wf    = (const float*)d_in[17];
  const float* gf    = (const float*)d_in[18];
  const float* bfv   = (const float*)d_in[19];

  float* w      = (float*)d_ws;
  float* g0buf  = w;                    // 262144
  float* g1buf  = w + 262144;           // 262144
  float* feats  = w + 524288;           // 4096*304 = 1245184
  float* fused  = w + 1769472;          // 4096*128 = 524288
  float* part0  = w + 2293760;          // 1024*28 = 28672 (pad to 32768)
  float* part1  = w + 2326528;          // 256*96 = 24576
  float* part2  = w + 2351104;          // 512*256 = 131072
  int*   cnt    = (int*)(w + 2482176);  // 8192 ints

  hipLaunchKernelGGL(mega_kernel,  dim3(5120), dim3(256), 0, stream,
                     kp, pts, pfeat, bev, strd, g0buf, g1buf, cnt, part0, feats);
  hipLaunchKernelGGL(stats1_kernel, dim3(256), dim3(256), 0, stream,
                     g0buf, g1buf, part0,
                     W0s0, g0s0, b0s0, W0s1, g0s1, b0s1, W1s0, W1s1, part1);
  hipLaunchKernelGGL(pool_kernel,  dim3(256),  dim3(256), 0, stream,
                     g0buf, g1buf, cnt, part0, part1,
                     W0s0, g0s0, b0s0, W0s1, g0s1, b0s1,
                     W1s0, g1s0, b1s0, W1s1, g1s1, b1s1, feats);
  hipLaunchKernelGGL(fused_kernel, dim3(512),  dim3(128), 0, stream, feats, Wf, fused, part2);
  hipLaunchKernelGGL(out_kernel,   dim3(128),  dim3(256), 0, stream, fused, part2, gf, bfv, (float*)d_out);
}